// Round 2
// baseline (4062.477 us; speedup 1.0000x reference)
//
#include <hip/hip_runtime.h>

// ---------------------------------------------------------------------------
// ShoppingLSTM: 12-layer LSTM (layer0 own weights, layers1..11 shared),
// B=128, S=256, H=EMB=256, OUT=10.
//
// Diagonal-wavefront persistent kernel: layer l at tick k does t = k-l
// => 267 ticks. 192 blocks = 12 layers x 16 col-slices. Weights (64 gate-cols
// x K=512 fp16) in 256 VGPRs/wave for the whole kernel.
//
// R2 change: ALL cross-block traffic (wt, hbuf, h32) via __hip_atomic_load/
// store RELAXED AGENT (8B/4B) — per-access device coherence, no cache-wide
// wbl2/buffer_inv fences (R1: 51k serialized cache ops = 6 ms + stale-L1
// races under graph replay). Barrier = vmcnt drain + syncthreads + 2-level
// monotone atomic counters only.
// ---------------------------------------------------------------------------

#define BB 128
#define SS 256
#define LL 12
#define NBLK 192
#define TICKS (SS + LL - 1)   // 267
#define AGENT __HIP_MEMORY_SCOPE_AGENT

typedef _Float16 half8 __attribute__((ext_vector_type(8)));
typedef _Float16 half4 __attribute__((ext_vector_type(4)));
typedef float f32x4 __attribute__((ext_vector_type(4)));

union U16 { unsigned long long u[2]; half8 h; };
union U8  { unsigned long long u;    half4 h; };

__device__ __forceinline__ unsigned long long ald(const _Float16* p) {
    return __hip_atomic_load((unsigned long long*)p, __ATOMIC_RELAXED, AGENT);
}
__device__ __forceinline__ void ast(_Float16* p, unsigned long long v) {
    __hip_atomic_store((unsigned long long*)p, v, __ATOMIC_RELAXED, AGENT);
}
__device__ __forceinline__ half8 ld16(const _Float16* p) {
    U16 r; r.u[0] = ald(p); r.u[1] = ald(p + 4); return r.h;
}

__device__ __forceinline__ float sigf(float x) {
    return 1.0f / (1.0f + __expf(-x));
}
__device__ __forceinline__ float tanhf_fast(float x) {
    return 1.0f - 2.0f / (1.0f + __expf(2.0f * x));
}

__device__ __forceinline__ half8 cvt8(const float* p) {
    float4 u = *(const float4*)p;
    float4 v = *(const float4*)(p + 4);
    half8 h;
    h[0] = (_Float16)u.x; h[1] = (_Float16)u.y; h[2] = (_Float16)u.z; h[3] = (_Float16)u.w;
    h[4] = (_Float16)v.x; h[5] = (_Float16)v.y; h[6] = (_Float16)v.z; h[7] = (_Float16)v.w;
    return h;
}

// 2-level grid barrier: monotone counters, no resets, NO cache-maintenance
// fences. Data visibility comes from each access being agent-coherent; the
// per-wave vmcnt(0) + s_barrier guarantees all of the block's atomic stores
// reached the coherence point before thread 0 arrives.
__device__ __forceinline__ void gridbar(int* bar, int l, int e) {
    asm volatile("s_waitcnt vmcnt(0)" ::: "memory");
    __syncthreads();
    if (threadIdx.x == 0) {
        int a = __hip_atomic_fetch_add(&bar[l * 16], 1, __ATOMIC_RELAXED, AGENT);
        if (a == 16 * e - 1) {
            int r = __hip_atomic_fetch_add(&bar[192], 1, __ATOMIC_RELAXED, AGENT);
            if (r == 12 * e - 1) {
                __hip_atomic_store(&bar[200], e, __ATOMIC_RELAXED, AGENT);
            } else {
                while (__hip_atomic_load(&bar[200], __ATOMIC_RELAXED, AGENT) < e)
                    __builtin_amdgcn_s_sleep(1);
            }
        } else {
            while (__hip_atomic_load(&bar[200], __ATOMIC_RELAXED, AGENT) < e)
                __builtin_amdgcn_s_sleep(1);
        }
    }
    __syncthreads();
}

__global__ __launch_bounds__(256, 1) void lstm_wavefront(
    const int* __restrict__ xind,     // [128][256]
    const float* __restrict__ emb,    // [50000][256]
    const float* __restrict__ W0, const float* __restrict__ U0,
    const float* __restrict__ b0,
    const float* __restrict__ Wsh, const float* __restrict__ Ush,
    const float* __restrict__ bsh,
    const float* __restrict__ fcW, const float* __restrict__ fcb,
    float* __restrict__ out,          // [128][10]
    _Float16* __restrict__ wt,        // ws: [2][1024][512] transposed fp16 weights
    _Float16* __restrict__ hbuf,      // ws: [12][2][128][256] h ring
    float* __restrict__ h32,          // ws: [128][256] final h fp32
    int* __restrict__ bar)            // ws: barrier counters (memset 0)
{
    const int l    = blockIdx.x >> 4;
    const int s    = blockIdx.x & 15;
    const int wave = threadIdx.x >> 6;
    const int lane = threadIdx.x & 63;
    const int quad = lane >> 4;
    const int ln   = lane & 15;

    __shared__ float tile[32][33];
    __shared__ unsigned short hsm[128][16];   // h repack staging (4 KB)

    // ---- phase 0: transpose W/U fp32 [256][1024] -> wt fp16 [set][n][k] ----
    {
        const int rr = threadIdx.x >> 5;   // 0..7
        const int cc = threadIdx.x & 31;   // 0..31
        const int nl = threadIdx.x >> 3;   // 0..31
        const int kg = threadIdx.x & 7;    // 0..7
        for (int tidx = blockIdx.x; tidx < 1024; tidx += NBLK) {
            const int job   = tidx >> 8;        // 0:W0 1:U0 2:Ws 3:Us
            const int tk    = (tidx >> 5) & 7;
            const int tn    = tidx & 31;
            const float* src = (job == 0) ? W0 : (job == 1) ? U0 : (job == 2) ? Wsh : Ush;
            const int set   = job >> 1;
            const int khalf = job & 1;
            __syncthreads();
            #pragma unroll
            for (int r = 0; r < 4; ++r)
                tile[rr + r * 8][cc] = src[(size_t)(tk * 32 + rr + r * 8) * 1024 + tn * 32 + cc];
            __syncthreads();
            U8 pk;
            #pragma unroll
            for (int j = 0; j < 4; ++j)
                pk.h[j] = (_Float16)tile[kg * 4 + j][nl];
            ast(wt + ((size_t)(set * 1024 + tn * 32 + nl)) * 512 + khalf * 256 + tk * 32 + kg * 4,
                pk.u);
        }
    }
    int e = 1;
    gridbar(bar, l, e); e++;

    // ---- weight fragments -> registers (stay for all 267 ticks) ----
    // B-frag for mfma_f32_16x16x32_f16: n = lane&15, k = ks*32 + quad*8 + j
    half8 bf[4][16];
    {
        const int set = (l == 0) ? 0 : 1;
        #pragma unroll
        for (int q = 0; q < 4; ++q) {
            const _Float16* base = wt + ((size_t)(set * 1024 + q * 256 + s * 16 + ln)) * 512 + quad * 8;
            #pragma unroll
            for (int ks = 0; ks < 16; ++ks)
                bf[q][ks] = ld16(base + ks * 32);
        }
    }
    float bias_q[4];
    {
        const float* bv = (l == 0) ? b0 : bsh;
        #pragma unroll
        for (int q = 0; q < 4; ++q)
            bias_q[q] = bv[q * 256 + s * 16 + ln];
    }

    float creg[2][4];
    const int rowA = wave * 32 + ln;
    const int col  = s * 16 + ln;
    const int rrow = threadIdx.x >> 1;     // repack: row 0..127
    const int rch  = threadIdx.x & 1;      // repack: col-half

    for (int tick = 0; tick < TICKS; ++tick, ++e) {
        const int t = tick - l;
        if (t >= 0 && t < SS) {
            f32x4 acc[2][4];
            #pragma unroll
            for (int mt = 0; mt < 2; ++mt)
                #pragma unroll
                for (int q = 0; q < 4; ++q)
                    acc[mt][q] = (f32x4){0.f, 0.f, 0.f, 0.f};

            const int slot = (tick + 1) & 1;   // where tick-1 was written

            // ---- x-part: K 0..255 (W rows) ----
            if (l == 0) {
                const int i0 = xind[rowA * SS + t];
                const int i1 = xind[(rowA + 16) * SS + t];
                const float* e0 = emb + (size_t)i0 * 256 + quad * 8;
                const float* e1 = emb + (size_t)i1 * 256 + quad * 8;
                #pragma unroll
                for (int ks = 0; ks < 8; ++ks) {
                    half8 a0 = cvt8(e0 + ks * 32);
                    half8 a1 = cvt8(e1 + ks * 32);
                    #pragma unroll
                    for (int q = 0; q < 4; ++q) {
                        acc[0][q] = __builtin_amdgcn_mfma_f32_16x16x32_f16(a0, bf[q][ks], acc[0][q], 0, 0, 0);
                        acc[1][q] = __builtin_amdgcn_mfma_f32_16x16x32_f16(a1, bf[q][ks], acc[1][q], 0, 0, 0);
                    }
                }
            } else {
                const _Float16* xs = hbuf + ((size_t)((l - 1) * 2 + slot) * 128) * 256 + rowA * 256 + quad * 8;
                #pragma unroll
                for (int ks = 0; ks < 8; ++ks) {
                    half8 a0 = ld16(xs + ks * 32);
                    half8 a1 = ld16(xs + 16 * 256 + ks * 32);
                    #pragma unroll
                    for (int q = 0; q < 4; ++q) {
                        acc[0][q] = __builtin_amdgcn_mfma_f32_16x16x32_f16(a0, bf[q][ks], acc[0][q], 0, 0, 0);
                        acc[1][q] = __builtin_amdgcn_mfma_f32_16x16x32_f16(a1, bf[q][ks], acc[1][q], 0, 0, 0);
                    }
                }
            }

            // ---- h-part: K 256..511 (U rows); h(t=0)=0 ----
            if (t > 0) {
                const _Float16* hs = hbuf + ((size_t)(l * 2 + slot) * 128) * 256 + rowA * 256 + quad * 8;
                #pragma unroll
                for (int ks = 0; ks < 8; ++ks) {
                    half8 a0 = ld16(hs + ks * 32);
                    half8 a1 = ld16(hs + 16 * 256 + ks * 32);
                    #pragma unroll
                    for (int q = 0; q < 4; ++q) {
                        acc[0][q] = __builtin_amdgcn_mfma_f32_16x16x32_f16(a0, bf[q][ks + 8], acc[0][q], 0, 0, 0);
                        acc[1][q] = __builtin_amdgcn_mfma_f32_16x16x32_f16(a1, bf[q][ks + 8], acc[1][q], 0, 0, 0);
                    }
                }
            }

            // ---- LSTM cell (D layout: col=lane&15, row=quad*4+reg) ----
            #pragma unroll
            for (int mt = 0; mt < 2; ++mt) {
                #pragma unroll
                for (int r = 0; r < 4; ++r) {
                    float gi = acc[mt][0][r] + bias_q[0];
                    float gf = acc[mt][1][r] + bias_q[1];
                    float gg = acc[mt][2][r] + bias_q[2];
                    float go = acc[mt][3][r] + bias_q[3];
                    float cold = (t == 0) ? 0.0f : creg[mt][r];
                    float cnew = sigf(gf) * cold + sigf(gi) * tanhf_fast(gg);
                    creg[mt][r] = cnew;
                    float h = sigf(go) * tanhf_fast(cnew);
                    int row = wave * 32 + mt * 16 + quad * 4 + r;
                    _Float16 hh = (_Float16)h;
                    hsm[row][ln] = *(unsigned short*)&hh;
                    if (l == LL - 1 && t == SS - 1)
                        __hip_atomic_store(&h32[row * 256 + col], h, __ATOMIC_RELAXED, AGENT);
                }
            }
            __syncthreads();
            // repack LDS -> 8B agent-coherent stores (2 per thread)
            {
                _Float16* hd = hbuf + ((size_t)(l * 2 + (tick & 1)) * 128) * 256
                             + rrow * 256 + s * 16 + rch * 8;
                unsigned long long v0 = *(const unsigned long long*)&hsm[rrow][rch * 8];
                unsigned long long v1 = *(const unsigned long long*)&hsm[rrow][rch * 8 + 4];
                ast(hd, v0);
                ast(hd + 4, v1);
            }
        }
        gridbar(bar, l, e);
    }

    // ---- final FC on block 0 ----
    if (blockIdx.x == 0) {
        for (int idx = threadIdx.x; idx < BB * 10; idx += 256) {
            int b = idx / 10, o = idx % 10;
            float a = fcb[o];
            for (int d = 0; d < 256; ++d) {
                float hv = __hip_atomic_load(&h32[b * 256 + d], __ATOMIC_RELAXED, AGENT);
                a += hv * fcW[d * 10 + o];
            }
            out[idx] = a;
        }
    }
}

extern "C" void kernel_launch(void* const* d_in, const int* in_sizes, int n_in,
                              void* d_out, int out_size, void* d_ws, size_t ws_size,
                              hipStream_t stream) {
    const int*   xind = (const int*)d_in[0];
    const float* emb  = (const float*)d_in[1];
    const float* W0   = (const float*)d_in[2];
    const float* U0   = (const float*)d_in[3];
    const float* b0   = (const float*)d_in[4];
    const float* Wsh  = (const float*)d_in[5];
    const float* Ush  = (const float*)d_in[6];
    const float* bsh  = (const float*)d_in[7];
    const float* fcW  = (const float*)d_in[8];
    const float* fcb  = (const float*)d_in[9];
    float* out = (float*)d_out;

    char* ws = (char*)d_ws;
    _Float16* wt   = (_Float16*)ws;                               // 2 MB
    _Float16* hbuf = (_Float16*)(ws + 2097152);                   // 1.5 MB
    float*    h32  = (float*)(ws + 2097152 + 1572864);            // 128 KB
    int*      bar  = (int*)(ws + 2097152 + 1572864 + 131072);     // 4 KB

    hipMemsetAsync(bar, 0, 4096, stream);
    hipLaunchKernelGGL(lstm_wavefront, dim3(NBLK), dim3(256), 0, stream,
                       xind, emb, W0, U0, b0, Wsh, Ush, bsh, fcW, fcb, out,
                       wt, hbuf, h32, bar);
}

// Round 4
// 3383.738 us; speedup vs baseline: 1.2006x; 1.2006x over previous
//
#include <hip/hip_runtime.h>

// ---------------------------------------------------------------------------
// ShoppingLSTM: 12-layer LSTM (layer0 own weights, layers1..11 shared),
// B=128, S=256, H=EMB=256, OUT=10.
//
// R4: dataflow-pipelined persistent kernel (R3 protocol — per-layer monotone
// progress counters, ring-buffered h exchange) with SAFE batched coherent
// loads: each batch of 16 global_load_dwordx4 sc0 sc1 carries its own
// terminal s_waitcnt vmcnt(0) inside ONE asm block, outputs early-clobbered.
// R3's "+v" tie trick let the allocator copy/spill not-yet-landed registers
// (and alias async dests with address pairs) -> GPU fault. Self-contained
// batches make the compiler's value model match hardware exactly.
// ---------------------------------------------------------------------------

#define BB 128
#define SS 256
#define LL 12
#define NBLK 192
#define AGENT __HIP_MEMORY_SCOPE_AGENT

typedef _Float16 half8 __attribute__((ext_vector_type(8)));
typedef float f32x4 __attribute__((ext_vector_type(4)));

union U8 { unsigned long long u; _Float16 h[4]; };

__device__ __forceinline__ float sigf(float x) {
    return 1.0f / (1.0f + __expf(-x));
}
__device__ __forceinline__ float tanhf_fast(float x) {
    return 1.0f - 2.0f / (1.0f + __expf(2.0f * x));
}
__device__ __forceinline__ half8 cvt8(const float* p) {
    float4 u = *(const float4*)p;
    float4 v = *(const float4*)(p + 4);
    half8 h;
    h[0] = (_Float16)u.x; h[1] = (_Float16)u.y; h[2] = (_Float16)u.z; h[3] = (_Float16)u.w;
    h[4] = (_Float16)v.x; h[5] = (_Float16)v.y; h[6] = (_Float16)v.z; h[7] = (_Float16)v.w;
    return h;
}
__device__ __forceinline__ int pld(const int* p) {
    return __hip_atomic_load(p, __ATOMIC_RELAXED, AGENT);
}

// ---- batched device-coherent loads -----------------------------------------
// Two bases (M-tile 0 / M-tile 1), 8 frags each at byte offsets k*64.
// Loads + terminal waitcnt in ONE asm: values truly ready at asm exit.
// "=&v": async dest writes must never alias the address registers.
__device__ __forceinline__ void ld8x2(const _Float16* p0, const _Float16* p1,
                                      half8 (&r0)[8], half8 (&r1)[8]) {
    asm volatile(
        "global_load_dwordx4 %0, %16, off sc0 sc1\n\t"
        "global_load_dwordx4 %1, %16, off offset:64 sc0 sc1\n\t"
        "global_load_dwordx4 %2, %16, off offset:128 sc0 sc1\n\t"
        "global_load_dwordx4 %3, %16, off offset:192 sc0 sc1\n\t"
        "global_load_dwordx4 %4, %16, off offset:256 sc0 sc1\n\t"
        "global_load_dwordx4 %5, %16, off offset:320 sc0 sc1\n\t"
        "global_load_dwordx4 %6, %16, off offset:384 sc0 sc1\n\t"
        "global_load_dwordx4 %7, %16, off offset:448 sc0 sc1\n\t"
        "global_load_dwordx4 %8, %17, off sc0 sc1\n\t"
        "global_load_dwordx4 %9, %17, off offset:64 sc0 sc1\n\t"
        "global_load_dwordx4 %10, %17, off offset:128 sc0 sc1\n\t"
        "global_load_dwordx4 %11, %17, off offset:192 sc0 sc1\n\t"
        "global_load_dwordx4 %12, %17, off offset:256 sc0 sc1\n\t"
        "global_load_dwordx4 %13, %17, off offset:320 sc0 sc1\n\t"
        "global_load_dwordx4 %14, %17, off offset:384 sc0 sc1\n\t"
        "global_load_dwordx4 %15, %17, off offset:448 sc0 sc1\n\t"
        "s_waitcnt vmcnt(0)"
        : "=&v"(r0[0]), "=&v"(r0[1]), "=&v"(r0[2]), "=&v"(r0[3]),
          "=&v"(r0[4]), "=&v"(r0[5]), "=&v"(r0[6]), "=&v"(r0[7]),
          "=&v"(r1[0]), "=&v"(r1[1]), "=&v"(r1[2]), "=&v"(r1[3]),
          "=&v"(r1[4]), "=&v"(r1[5]), "=&v"(r1[6]), "=&v"(r1[7])
        : "v"(p0), "v"(p1)
        : "memory");
}
// One base, 16 frags at byte offsets k*64 (weight fragments, one-time).
__device__ __forceinline__ void ld16w(const _Float16* p, half8 (&r)[16]) {
    asm volatile(
        "global_load_dwordx4 %0, %16, off sc0 sc1\n\t"
        "global_load_dwordx4 %1, %16, off offset:64 sc0 sc1\n\t"
        "global_load_dwordx4 %2, %16, off offset:128 sc0 sc1\n\t"
        "global_load_dwordx4 %3, %16, off offset:192 sc0 sc1\n\t"
        "global_load_dwordx4 %4, %16, off offset:256 sc0 sc1\n\t"
        "global_load_dwordx4 %5, %16, off offset:320 sc0 sc1\n\t"
        "global_load_dwordx4 %6, %16, off offset:384 sc0 sc1\n\t"
        "global_load_dwordx4 %7, %16, off offset:448 sc0 sc1\n\t"
        "global_load_dwordx4 %8, %16, off offset:512 sc0 sc1\n\t"
        "global_load_dwordx4 %9, %16, off offset:576 sc0 sc1\n\t"
        "global_load_dwordx4 %10, %16, off offset:640 sc0 sc1\n\t"
        "global_load_dwordx4 %11, %16, off offset:704 sc0 sc1\n\t"
        "global_load_dwordx4 %12, %16, off offset:768 sc0 sc1\n\t"
        "global_load_dwordx4 %13, %16, off offset:832 sc0 sc1\n\t"
        "global_load_dwordx4 %14, %16, off offset:896 sc0 sc1\n\t"
        "global_load_dwordx4 %15, %16, off offset:960 sc0 sc1\n\t"
        "s_waitcnt vmcnt(0)"
        : "=&v"(r[0]), "=&v"(r[1]), "=&v"(r[2]), "=&v"(r[3]),
          "=&v"(r[4]), "=&v"(r[5]), "=&v"(r[6]), "=&v"(r[7]),
          "=&v"(r[8]), "=&v"(r[9]), "=&v"(r[10]), "=&v"(r[11]),
          "=&v"(r[12]), "=&v"(r[13]), "=&v"(r[14]), "=&v"(r[15])
        : "v"(p)
        : "memory");
}
__device__ __forceinline__ void stcg(_Float16* p, half8 v) {
    asm volatile("global_store_dwordx4 %0, %1, off sc0 sc1" :: "v"(p), "v"(v) : "memory");
}
__device__ __forceinline__ void vdrain() {
    asm volatile("s_waitcnt vmcnt(0)" ::: "memory");
}

// bar layout (ints, memset 0 each launch):
//   bar[32]          init-barrier counter
//   bar[(4+l)*16]    arr[l]  (arrive counts, monotone)
//   bar[(20+l)*16]   prog[l] (completed steps of layer l)
#define ARR(l)  ((4 + (l)) * 16)
#define PROG(l) ((20 + (l)) * 16)

__global__ __launch_bounds__(256, 1) void lstm_wavefront(
    const int* __restrict__ xind,     // [128][256]
    const float* __restrict__ emb,    // [50000][256]
    const float* __restrict__ W0, const float* __restrict__ U0,
    const float* __restrict__ b0,
    const float* __restrict__ Wsh, const float* __restrict__ Ush,
    const float* __restrict__ bsh,
    const float* __restrict__ fcW, const float* __restrict__ fcb,
    float* __restrict__ out,          // [128][10]
    _Float16* __restrict__ wt,        // ws: [2][1024][512] transposed fp16 weights
    _Float16* __restrict__ hbuf,      // ws: [12][ring][128][256] h ring
    float* __restrict__ h32,          // ws: [128][256] final h fp32
    int* __restrict__ bar,            // ws: counters (memset 0)
    int ring, int hmask)
{
    const int l    = blockIdx.x >> 4;
    const int s    = blockIdx.x & 15;
    const int wave = threadIdx.x >> 6;
    const int lane = threadIdx.x & 63;
    const int quad = lane >> 4;
    const int ln   = lane & 15;

    __shared__ float tile[32][33];
    __shared__ unsigned short hsm[128][16];

    // ---- phase 0: transpose W/U fp32 [256][1024] -> wt fp16 [set][n][k] ----
    {
        const int rr = threadIdx.x >> 5;
        const int cc = threadIdx.x & 31;
        const int nl = threadIdx.x >> 3;
        const int kg = threadIdx.x & 7;
        for (int tidx = blockIdx.x; tidx < 1024; tidx += NBLK) {
            const int job   = tidx >> 8;        // 0:W0 1:U0 2:Ws 3:Us
            const int tk    = (tidx >> 5) & 7;
            const int tn    = tidx & 31;
            const float* src = (job == 0) ? W0 : (job == 1) ? U0 : (job == 2) ? Wsh : Ush;
            const int set   = job >> 1;
            const int khalf = job & 1;
            __syncthreads();
            #pragma unroll
            for (int r = 0; r < 4; ++r)
                tile[rr + r * 8][cc] = src[(size_t)(tk * 32 + rr + r * 8) * 1024 + tn * 32 + cc];
            __syncthreads();
            U8 pk;
            #pragma unroll
            for (int j = 0; j < 4; ++j)
                pk.h[j] = (_Float16)tile[kg * 4 + j][nl];
            __hip_atomic_store(
                (unsigned long long*)(wt + ((size_t)(set * 1024 + tn * 32 + nl)) * 512
                                      + khalf * 256 + tk * 32 + kg * 4),
                pk.u, __ATOMIC_RELAXED, AGENT);
        }
    }
    // ---- init barrier (once) ----
    vdrain();
    __syncthreads();
    if (threadIdx.x == 0) {
        __hip_atomic_fetch_add(&bar[32], 1, __ATOMIC_RELAXED, AGENT);
        while (pld(&bar[32]) < NBLK) __builtin_amdgcn_s_sleep(2);
    }
    __syncthreads();

    // ---- weight fragments -> registers (stay for all 256 steps) ----
    // B-frag for mfma_f32_16x16x32_f16: n = lane&15, k = ks*32 + quad*8 + j
    half8 bf[4][16];
    {
        const int set = (l == 0) ? 0 : 1;
        #pragma unroll
        for (int q = 0; q < 4; ++q)
            ld16w(wt + ((size_t)(set * 1024 + q * 256 + s * 16 + ln)) * 512 + quad * 8,
                  bf[q]);
    }
    float bias_q[4];
    {
        const float* bv = (l == 0) ? b0 : bsh;
        #pragma unroll
        for (int q = 0; q < 4; ++q)
            bias_q[q] = bv[q * 256 + s * 16 + ln];
    }

    float creg[2][4];
    const int rowA = wave * 32 + ln;
    const int col  = s * 16 + ln;
    const int rrow = threadIdx.x >> 1;
    const int rch  = threadIdx.x & 1;

    for (int t = 0; t < SS; ++t) {
        // ---- waits spread over 3 waves (latency = max, not sum) ----
        if (threadIdx.x == 0) {
            if (l > 0)
                while (pld(&bar[PROG(l - 1)]) < t + 1) __builtin_amdgcn_s_sleep(1);
        } else if (threadIdx.x == 64) {
            if (t > 0)
                while (pld(&bar[PROG(l)]) < t) __builtin_amdgcn_s_sleep(1);
        } else if (threadIdx.x == 128) {
            if (l < LL - 1 && t >= ring)
                while (pld(&bar[PROG(l + 1)]) < t - ring + 1) __builtin_amdgcn_s_sleep(1);
        }
        __syncthreads();

        f32x4 acc[2][4];
        #pragma unroll
        for (int mt = 0; mt < 2; ++mt)
            #pragma unroll
            for (int q = 0; q < 4; ++q)
                acc[mt][q] = (f32x4){0.f, 0.f, 0.f, 0.f};

        // ---- x-part: K 0..255 (W rows) ----
        if (l == 0) {
            const int i0 = xind[rowA * SS + t];
            const int i1 = xind[(rowA + 16) * SS + t];
            const float* e0 = emb + (size_t)i0 * 256 + quad * 8;
            const float* e1 = emb + (size_t)i1 * 256 + quad * 8;
            #pragma unroll
            for (int ks = 0; ks < 8; ++ks) {
                half8 a0 = cvt8(e0 + ks * 32);
                half8 a1 = cvt8(e1 + ks * 32);
                #pragma unroll
                for (int q = 0; q < 4; ++q) {
                    acc[0][q] = __builtin_amdgcn_mfma_f32_16x16x32_f16(a0, bf[q][ks], acc[0][q], 0, 0, 0);
                    acc[1][q] = __builtin_amdgcn_mfma_f32_16x16x32_f16(a1, bf[q][ks], acc[1][q], 0, 0, 0);
                }
            }
        } else {
            half8 ax0[8], ax1[8];
            const _Float16* xs = hbuf + (((size_t)((l - 1) * ring + (t & hmask))) << 15)
                               + rowA * 256 + quad * 8;
            ld8x2(xs, xs + 4096, ax0, ax1);
            #pragma unroll
            for (int ks = 0; ks < 8; ++ks) {
                #pragma unroll
                for (int q = 0; q < 4; ++q) {
                    acc[0][q] = __builtin_amdgcn_mfma_f32_16x16x32_f16(ax0[ks], bf[q][ks], acc[0][q], 0, 0, 0);
                    acc[1][q] = __builtin_amdgcn_mfma_f32_16x16x32_f16(ax1[ks], bf[q][ks], acc[1][q], 0, 0, 0);
                }
            }
        }
        // ---- h-part: K 256..511 (U rows); h(t=0)=0 ----
        if (t > 0) {
            half8 ah0[8], ah1[8];
            const _Float16* hs = hbuf + (((size_t)(l * ring + ((t - 1) & hmask))) << 15)
                               + rowA * 256 + quad * 8;
            ld8x2(hs, hs + 4096, ah0, ah1);
            #pragma unroll
            for (int ks = 0; ks < 8; ++ks) {
                #pragma unroll
                for (int q = 0; q < 4; ++q) {
                    acc[0][q] = __builtin_amdgcn_mfma_f32_16x16x32_f16(ah0[ks], bf[q][ks + 8], acc[0][q], 0, 0, 0);
                    acc[1][q] = __builtin_amdgcn_mfma_f32_16x16x32_f16(ah1[ks], bf[q][ks + 8], acc[1][q], 0, 0, 0);
                }
            }
        }

        // ---- LSTM cell (D layout: col=lane&15, row=quad*4+reg) ----
        #pragma unroll
        for (int mt = 0; mt < 2; ++mt) {
            #pragma unroll
            for (int r = 0; r < 4; ++r) {
                float gi = acc[mt][0][r] + bias_q[0];
                float gf = acc[mt][1][r] + bias_q[1];
                float gg = acc[mt][2][r] + bias_q[2];
                float go = acc[mt][3][r] + bias_q[3];
                float cold = (t == 0) ? 0.0f : creg[mt][r];
                float cnew = sigf(gf) * cold + sigf(gi) * tanhf_fast(gg);
                creg[mt][r] = cnew;
                float h = sigf(go) * tanhf_fast(cnew);
                int row = wave * 32 + mt * 16 + quad * 4 + r;
                _Float16 hh = (_Float16)h;
                hsm[row][ln] = *(unsigned short*)&hh;
                if (l == LL - 1 && t == SS - 1)
                    __hip_atomic_store(&h32[row * 256 + col], h, __ATOMIC_RELAXED, AGENT);
            }
        }
        __syncthreads();
        // repack LDS -> one coherent 16B store per thread
        {
            _Float16* hd = hbuf + (((size_t)(l * ring + (t & hmask))) << 15)
                         + rrow * 256 + s * 16 + rch * 8;
            half8 v = *(const half8*)&hsm[rrow][rch * 8];
            stcg(hd, v);
        }
        vdrain();
        __syncthreads();
        // ---- publish progress ----
        if (threadIdx.x == 0) {
            int a = __hip_atomic_fetch_add(&bar[ARR(l)], 1, __ATOMIC_RELAXED, AGENT);
            if (a == 16 * (t + 1) - 1)
                __hip_atomic_store(&bar[PROG(l)], t + 1, __ATOMIC_RELAXED, AGENT);
        }
    }

    // ---- final FC on the 16 layer-11 blocks: block s -> batch rows s*8..s*8+7
    if (l == LL - 1) {
        if (threadIdx.x == 0)
            while (pld(&bar[PROG(LL - 1)]) < SS) __builtin_amdgcn_s_sleep(1);
        __syncthreads();
        int idx = threadIdx.x;
        if (idx < 80) {
            int b = s * 8 + idx / 10, o = idx % 10;
            float a0 = 0.f, a1 = 0.f, a2 = 0.f, a3 = 0.f;
            for (int d = 0; d < 256; d += 4) {
                a0 += __hip_atomic_load(&h32[b * 256 + d + 0], __ATOMIC_RELAXED, AGENT) * fcW[(d + 0) * 10 + o];
                a1 += __hip_atomic_load(&h32[b * 256 + d + 1], __ATOMIC_RELAXED, AGENT) * fcW[(d + 1) * 10 + o];
                a2 += __hip_atomic_load(&h32[b * 256 + d + 2], __ATOMIC_RELAXED, AGENT) * fcW[(d + 2) * 10 + o];
                a3 += __hip_atomic_load(&h32[b * 256 + d + 3], __ATOMIC_RELAXED, AGENT) * fcW[(d + 3) * 10 + o];
            }
            out[b * 10 + o] = fcb[o] + ((a0 + a1) + (a2 + a3));
        }
    }
}

extern "C" void kernel_launch(void* const* d_in, const int* in_sizes, int n_in,
                              void* d_out, int out_size, void* d_ws, size_t ws_size,
                              hipStream_t stream) {
    const int*   xind = (const int*)d_in[0];
    const float* emb  = (const float*)d_in[1];
    const float* W0   = (const float*)d_in[2];
    const float* U0   = (const float*)d_in[3];
    const float* b0   = (const float*)d_in[4];
    const float* Wsh  = (const float*)d_in[5];
    const float* Ush  = (const float*)d_in[6];
    const float* bsh  = (const float*)d_in[7];
    const float* fcW  = (const float*)d_in[8];
    const float* fcb  = (const float*)d_in[9];
    float* out = (float*)d_out;

    const size_t wtB = (size_t)2 * 1024 * 512 * 2;  // 2 MB
    auto need = [&](int r) {
        return wtB + (size_t)LL * r * 128 * 256 * 2 + 131072 + 4096;
    };
    int ring = (ws_size >= need(8)) ? 8 : (ws_size >= need(4)) ? 4 : 2;

    char* ws = (char*)d_ws;
    _Float16* wt   = (_Float16*)ws;
    _Float16* hbuf = (_Float16*)(ws + wtB);
    float*    h32  = (float*)(ws + wtB + (size_t)LL * ring * 128 * 256 * 2);
    int*      bar  = (int*)((char*)h32 + 131072);

    hipMemsetAsync(bar, 0, 4096, stream);
    hipLaunchKernelGGL(lstm_wavefront, dim3(NBLK), dim3(256), 0, stream,
                       xind, emb, W0, U0, b0, Wsh, Ush, bsh, fcW, fcb, out,
                       wt, hbuf, h32, bar, ring, ring - 1);
}